// Round 12
// baseline (346.631 us; speedup 1.0000x reference)
//
#include <hip/hip_runtime.h>
#include <stdint.h>

#define N_MODELC 1024
#define KV_MODELC 256
#define BATCH 4
#define SEQ 2048
#define NTOK (BATCH*SEQ)   // 8192
#define NZ 4
#define SCHUNK (SEQ/NZ)    // 512

typedef __attribute__((ext_vector_type(4))) float f32x4;
typedef __attribute__((ext_vector_type(4))) int   i32x4;
typedef __attribute__((ext_vector_type(8))) short s16x8;
typedef __attribute__((ext_vector_type(4))) short s16x4;

#define LOG2E 1.4426950408889634f
#define PSHIFT 32.0f

__device__ __forceinline__ unsigned short f2bf(float f){
  unsigned u = __builtin_bit_cast(unsigned, f);
  u = (u + 0x7FFFu + ((u>>16)&1u)) >> 16;
  return (unsigned short)u;
}
__device__ __forceinline__ float bf2f(unsigned short b){
  return __builtin_bit_cast(float, ((unsigned)b)<<16);
}

// ---------------- activation rmsnorm + int8 absmax quant (1024-wide rows) ----
__global__ __launch_bounds__(256) void k_actquant1024(
    const float* __restrict__ xq_in, const float* __restrict__ xk_in, const float* __restrict__ xv_in,
    int8_t* __restrict__ q8q, int8_t* __restrict__ q8k, int8_t* __restrict__ q8v,
    float* __restrict__ scq, float* __restrict__ sck, float* __restrict__ scv)
{
  int row = blockIdx.x, which = blockIdx.y, t = threadIdx.x;
  const float* x = (which==0)?xq_in:(which==1)?xk_in:xv_in;
  int8_t* q8 = (which==0)?q8q:(which==1)?q8k:q8v;
  float* sc = (which==0)?scq:(which==1)?sck:scv;
  const float* xr = x + (size_t)row*N_MODELC;
  float4 v = reinterpret_cast<const float4*>(xr)[t];
  float ss = v.x*v.x + v.y*v.y + v.z*v.z + v.w*v.w;
  float am = fmaxf(fmaxf(fabsf(v.x),fabsf(v.y)), fmaxf(fabsf(v.z),fabsf(v.w)));
  #pragma unroll
  for (int m=32;m;m>>=1){ ss += __shfl_xor(ss,m,64); am = fmaxf(am, __shfl_xor(am,m,64)); }
  __shared__ float red[8];
  int wid = t>>6;
  if ((t&63)==0){ red[wid]=ss; red[4+wid]=am; }
  __syncthreads();
  ss = red[0]+red[1]+red[2]+red[3];
  am = fmaxf(fmaxf(red[4],red[5]), fmaxf(red[6],red[7]));
  float rinv = rsqrtf(ss*(1.0f/N_MODELC) + 1e-6f);
  float clipv = fmaxf(am*rinv, 1e-5f);
  float qs = 127.0f/clipv;
  float fsc = rinv*qs;
  char4 o;
  o.x = (signed char)(int)fminf(127.f, fmaxf(-128.f, rintf(v.x*fsc)));
  o.y = (signed char)(int)fminf(127.f, fmaxf(-128.f, rintf(v.y*fsc)));
  o.z = (signed char)(int)fminf(127.f, fmaxf(-128.f, rintf(v.z*fsc)));
  o.w = (signed char)(int)fminf(127.f, fmaxf(-128.f, rintf(v.w*fsc)));
  reinterpret_cast<char4*>(q8 + (size_t)row*N_MODELC)[t] = o;
  if (t==0) sc[row] = clipv*(1.0f/127.0f);
}

// ---------------- same for 256-wide rows (one wave per row) ------------------
__global__ __launch_bounds__(64) void k_actquant256(
    const float* __restrict__ X, int8_t* __restrict__ q8, float* __restrict__ sc)
{
  int row = blockIdx.x, l = threadIdx.x;
  float4 v = reinterpret_cast<const float4*>(X + (size_t)row*KV_MODELC)[l];
  float ss = v.x*v.x + v.y*v.y + v.z*v.z + v.w*v.w;
  float am = fmaxf(fmaxf(fabsf(v.x),fabsf(v.y)), fmaxf(fabsf(v.z),fabsf(v.w)));
  #pragma unroll
  for (int m=32;m;m>>=1){ ss += __shfl_xor(ss,m,64); am = fmaxf(am, __shfl_xor(am,m,64)); }
  float rinv = rsqrtf(ss*(1.0f/KV_MODELC) + 1e-6f);
  float clipv = fmaxf(am*rinv, 1e-5f);
  float qs = 127.0f/clipv;
  float fsc = rinv*qs;
  char4 o;
  o.x = (signed char)(int)fminf(127.f, fmaxf(-128.f, rintf(v.x*fsc)));
  o.y = (signed char)(int)fminf(127.f, fmaxf(-128.f, rintf(v.y*fsc)));
  o.z = (signed char)(int)fminf(127.f, fmaxf(-128.f, rintf(v.z*fsc)));
  o.w = (signed char)(int)fminf(127.f, fmaxf(-128.f, rintf(v.w*fsc)));
  reinterpret_cast<char4*>(q8 + (size_t)row*KV_MODELC)[l] = o;
  if (l==0) sc[row] = clipv*(1.0f/127.0f);
}

// ---------------- weight absmean: stage 1 ------------------------------------
__global__ __launch_bounds__(256) void k_wabs_partial(
    const float* __restrict__ Wq, const float* __restrict__ Wk,
    const float* __restrict__ Wv, const float* __restrict__ Wo, float* __restrict__ partial)
{
  int mat = blockIdx.y;
  const float* w = (mat==0)?Wq:(mat==1)?Wk:(mat==2)?Wv:Wo;
  int n = (mat==0)?(N_MODELC*N_MODELC):(KV_MODELC*N_MODELC);
  float s = 0.f;
  for (int i = blockIdx.x*256 + threadIdx.x; i < n; i += 256*256) s += fabsf(w[i]);
  #pragma unroll
  for (int m=32;m;m>>=1) s += __shfl_xor(s,m,64);
  __shared__ float red[4];
  int wid = threadIdx.x>>6;
  if ((threadIdx.x&63)==0) red[wid]=s;
  __syncthreads();
  if (threadIdx.x==0) partial[mat*256 + blockIdx.x] = red[0]+red[1]+red[2]+red[3];
}

// ---------------- weight absmean: stage 2 ------------------------------------
__global__ __launch_bounds__(256) void k_wfinal(const float* __restrict__ partial, float* __restrict__ wfac)
{
  int mat = blockIdx.x, t = threadIdx.x;
  float s = partial[mat*256 + t];
  #pragma unroll
  for (int m=32;m;m>>=1) s += __shfl_xor(s,m,64);
  __shared__ float red[4];
  int wid = t>>6;
  if ((t&63)==0) red[wid]=s;
  __syncthreads();
  if (t==0){
    float tot = red[0]+red[1]+red[2]+red[3];
    float n = (mat==0)?(float)(N_MODELC*N_MODELC):(float)(KV_MODELC*N_MODELC);
    wfac[mat] = fmaxf(tot/n, 1e-5f);
  }
}

// ---------------- ternarize weights (Wq also group-summed) -------------------
__global__ __launch_bounds__(256) void k_tern(
    const float* __restrict__ Wq, const float* __restrict__ Wk,
    const float* __restrict__ Wv, const float* __restrict__ Wo,
    const float* __restrict__ wfac,
    int8_t* __restrict__ Wqs, int8_t* __restrict__ Wkt,
    int8_t* __restrict__ Wvt, int8_t* __restrict__ Wot)
{
  int mat = blockIdx.y;
  int idx = blockIdx.x*256 + threadIdx.x;
  if (mat==0){
    float s = 1.0f/wfac[0];
    int op = idx>>10, i = idx&1023;
    int kv = op>>6, d = op&63;
    int acc = 0;
    #pragma unroll
    for (int g=0; g<4; g++){
      float w = Wq[(size_t)(kv*256 + g*64 + d)*N_MODELC + i];
      float r = fminf(1.f, fmaxf(-1.f, rintf(w*s)));
      acc += (int)r;
    }
    Wqs[idx] = (int8_t)acc;
  } else {
    const float* w = (mat==1)?Wk:(mat==2)?Wv:Wo;
    int8_t* o = (mat==1)?Wkt:(mat==2)?Wvt:Wot;
    float s = 1.0f/wfac[mat];
    float r = fminf(1.f, fmaxf(-1.f, rintf(w[idx]*s)));
    o[idx] = (int8_t)r;
  }
}

// ---------------- int8 GEMM (K=1024), 8 waves, k-split -----------------------
// MODE 0: Q -> bf16 head-packed Qh[bkv][s][64], x0.125, group-summed bias
// MODE 1: K -> bf16 head-packed Kh[bkv][s][64]
// MODE 2: V -> bf16 head-tiled Vh[bkv][sTile][64d][64s] via LDS transpose
template<int MODE>
__global__ __launch_bounds__(512) void k_gemm_i8_1024(
    const int8_t* __restrict__ A, const int8_t* __restrict__ B,
    const float* __restrict__ rowscale, const float* __restrict__ wfac, int wfi,
    const float* __restrict__ bias, unsigned short* __restrict__ outp)
{
  __shared__ i32x4 redk[4][4][64];                      // 16 KB
  __shared__ unsigned short tlds[(MODE==2)?64:1][72];
  const int KDIM = 1024;
  int mb = blockIdx.x*64, nb = blockIdx.y*64;
  int w = threadIdx.x>>6, l = threadIdx.x&63, lr = l&15, lk = l>>4;
  int rw = w&3, kh = w>>2;
  const int8_t* Ap = A + (size_t)(mb + rw*16 + lr)*KDIM + kh*512 + lk*16;
  const int8_t* Bp = B + (size_t)(nb + lr)*KDIM + kh*512 + lk*16;
  i32x4 acc[4];
  #pragma unroll
  for (int f=0; f<4; f++) acc[f] = i32x4{0,0,0,0};
  #pragma unroll 4
  for (int kk=0; kk<512; kk+=64){
    i32x4 a = *reinterpret_cast<const i32x4*>(Ap + kk);
    #pragma unroll
    for (int f=0; f<4; f++){
      i32x4 b = *reinterpret_cast<const i32x4*>(Bp + (size_t)f*16*KDIM + kk);
      acc[f] = __builtin_amdgcn_mfma_i32_16x16x64_i8(a, b, acc[f], 0, 0, 0);
    }
  }
  if (kh==1){
    #pragma unroll
    for (int f=0; f<4; f++) redk[rw][f][l] = acc[f];
  }
  __syncthreads();
  if (kh==0){
    float wf = wfac[wfi];
    #pragma unroll
    for (int f=0; f<4; f++){
      acc[f] += redk[rw][f][l];
      int col = nb + f*16 + lr;
      float bval;
      if constexpr (MODE==0){
        int kv = col>>6, d = col&63;
        const float* bb = bias + kv*256 + d;
        bval = bb[0]+bb[64]+bb[128]+bb[192];
      } else {
        bval = bias[col];
      }
      #pragma unroll
      for (int r=0; r<4; r++){
        int row = mb + rw*16 + lk*4 + r;
        float val = (float)acc[f][r] * (rowscale[row]*wf) + bval;
        if constexpr (MODE==0){
          int bb2 = row>>11, s = row&2047, kvh = col>>6, d = col&63;
          outp[(((size_t)(bb2*4+kvh))*SEQ + s)*64 + d] = f2bf(0.125f*val);
        } else if constexpr (MODE==1){
          int bb2 = row>>11, s = row&2047, kvh = col>>6, d = col&63;
          outp[(((size_t)(bb2*4+kvh))*SEQ + s)*64 + d] = f2bf(val);
        } else {
          tlds[f*16+lr][rw*16 + lk*4 + r] = f2bf(val);
        }
      }
    }
  }
  if constexpr (MODE==2){
    __syncthreads();
    int u = threadIdx.x;
    int col = u>>3, part = u&7;
    int b = mb>>11, s0 = mb&2047;
    int bkv = b*4 + blockIdx.y, sT = s0>>6;
    s16x8 vv = *reinterpret_cast<const s16x8*>(&tlds[col][part*8]);
    *reinterpret_cast<s16x8*>(
        &outp[(((size_t)(bkv*32 + sT))*64 + col)*64 + part*8]) = vv;
  }
}

// ---------------- int8 GEMM (K=256) output bitlinear -> f32 d_out ------------
__global__ __launch_bounds__(256) void k_gemm_o(
    const int8_t* __restrict__ A, const int8_t* __restrict__ B,
    const float* __restrict__ rowscale, const float* __restrict__ wfac,
    const float* __restrict__ bias, float* __restrict__ outp)
{
  const int KDIM = 256;
  int mb = blockIdx.x*64, nb = blockIdx.y*64;
  int w = threadIdx.x>>6, l = threadIdx.x&63, lr = l&15, lk = l>>4;
  const int8_t* Ap = A + (size_t)(mb + w*16 + lr)*KDIM + lk*16;
  const int8_t* Bp = B + (size_t)(nb + lr)*KDIM + lk*16;
  i32x4 acc[4];
  #pragma unroll
  for (int f=0; f<4; f++) acc[f] = i32x4{0,0,0,0};
  #pragma unroll
  for (int kk=0; kk<KDIM; kk+=64){
    i32x4 a = *reinterpret_cast<const i32x4*>(Ap + kk);
    #pragma unroll
    for (int f=0; f<4; f++){
      i32x4 b = *reinterpret_cast<const i32x4*>(Bp + (size_t)f*16*KDIM + kk);
      acc[f] = __builtin_amdgcn_mfma_i32_16x16x64_i8(a, b, acc[f], 0, 0, 0);
    }
  }
  float wf = wfac[3];
  #pragma unroll
  for (int f=0; f<4; f++){
    int col = nb + f*16 + lr;
    float bval = bias[col];
    #pragma unroll
    for (int r=0; r<4; r++){
      int row = mb + w*16 + lk*4 + r;
      outp[(size_t)row*N_MODELC + col] = (float)acc[f][r]*(rowscale[row]*wf) + bval;
    }
  }
}

// ---------------- attn: ONE pass -> packed p~ + l partials + PV partials -----
// Fixed-shift p~ = 2^(e*log2e-32) (unnormalized). Grid (64,16,NZ), 2-wave
// blocks -> 32 waves/CU. Per tile: QK MFMA -> exp2 -> bf16 LDS (proven) ->
// PV MFMA + ones-MFMA l; readback stores PACKED bf16 pairs (8B/lane) into
// the FIRST HALF of each attn row's f32 slots (slot j = s pair 2j,2j+1).
// No second QK pass anywhere.
__global__ __launch_bounds__(128) void k_attn_pv2(
    const unsigned short* __restrict__ Qh, const unsigned short* __restrict__ Kh,
    const unsigned short* __restrict__ Vh,
    float* __restrict__ attn, float* __restrict__ lpart, float* __restrict__ pvpart)
{
  __shared__ unsigned short plds[2][16][64];   // 4 KB, wave-private tiles
  int bkv = blockIdx.y, z = blockIdx.z;
  int w = threadIdx.x>>6, l = threadIdx.x&63, lr = l&15, lk = l>>4;
  int rowt = blockIdx.x*32 + w*16;
  size_t tq = ((size_t)bkv*SEQ + rowt + lr)*64 + lk*8;
  s16x8 qa0 = *reinterpret_cast<const s16x8*>(Qh + tq);
  s16x8 qa1 = *reinterpret_cast<const s16x8*>(Qh + tq + 32);
  const unsigned short* kbase = Kh + (size_t)bkv*SEQ*64 + lk*8;
  const unsigned short* vbase = Vh + (size_t)bkv*32*4096 + lk*8;

  s16x8 ones;
  #pragma unroll
  for (int i=0;i<8;i++) ones[i] = (short)0x3F80;   // bf16 1.0

  f32x4 acco[4];
  #pragma unroll
  for (int dt=0; dt<4; dt++) acco[dt] = f32x4{0.f,0.f,0.f,0.f};
  f32x4 accl = {0.f,0.f,0.f,0.f};

  int qwl = lk*4;                 // local write-row base (+r)
  int rswl = (lr&7)<<3;           // PV read swizzle base (local row = lr)
  // u32 view of this block's attn rows (packed bf16 pairs in first half)
  unsigned* arow32 = (unsigned*)(attn + (size_t)bkv*SEQ*SEQ + (size_t)rowt*SEQ);

  for (int st=z*SCHUNK; st<z*SCHUNK+SCHUNK; st+=64){
    #pragma unroll
    for (int sub=0; sub<4; sub++){
      int s0 = st + sub*16;
      const unsigned short* kp = kbase + (size_t)(s0+lr)*64;
      s16x8 k0 = *reinterpret_cast<const s16x8*>(kp);
      s16x8 k1 = *reinterpret_cast<const s16x8*>(kp + 32);
      f32x4 acc = {0.f,0.f,0.f,0.f};
      acc = __builtin_amdgcn_mfma_f32_16x16x32_bf16(qa0, k0, acc, 0,0,0);
      acc = __builtin_amdgcn_mfma_f32_16x16x32_bf16(qa1, k1, acc, 0,0,0);
      int slocal = sub*16 + lr;
      #pragma unroll
      for (int r=0;r<4;r++){
        float p = __builtin_amdgcn_exp2f(fmaf(acc[r], LOG2E, -PSHIFT));
        int sw = (slocal & 7) | ((((slocal>>3) ^ ((qwl+r)&7)))<<3);
        plds[w][qwl + r][sw] = f2bf(p);
      }
    }
    // PV + l over this 64-s block (wave-private LDS, unnormalized p~)
    s16x8 a0 = *reinterpret_cast<const s16x8*>(&plds[w][lr][(lk<<3) ^ rswl]);
    s16x8 a1 = *reinterpret_cast<const s16x8*>(&plds[w][lr][((4+lk)<<3) ^ rswl]);
    accl = __builtin_amdgcn_mfma_f32_16x16x32_bf16(a0, ones, accl, 0,0,0);
    accl = __builtin_amdgcn_mfma_f32_16x16x32_bf16(a1, ones, accl, 0,0,0);
    const unsigned short* vt = vbase + (size_t)(st>>6)*4096;
    #pragma unroll
    for (int dt=0; dt<4; dt++){
      const unsigned short* vp = vt + (size_t)(dt*16+lr)*64;
      s16x8 b0 = *reinterpret_cast<const s16x8*>(vp);
      s16x8 b1 = *reinterpret_cast<const s16x8*>(vp + 32);
      acco[dt] = __builtin_amdgcn_mfma_f32_16x16x32_bf16(a0, b0, acco[dt], 0,0,0);
      acco[dt] = __builtin_amdgcn_mfma_f32_16x16x32_bf16(a1, b1, acco[dt], 0,0,0);
    }
    // packed p~ readback: 16 lanes x 8B = 128B run per row (4 rows per j)
    #pragma unroll
    for (int j=0; j<4; j++){
      int rowl = j*4 + (l>>4);
      int sseg = l & 15;
      int chunk = sseg >> 1, half = sseg & 1;
      int off = ((chunk ^ (rowl&7)) << 3) + (half<<2);
      s16x4 pb = *reinterpret_cast<const s16x4*>(&plds[w][rowl][off]);
      *reinterpret_cast<uint2*>(&arow32[(size_t)rowl*SEQ + (st>>1) + sseg*2]) =
          *reinterpret_cast<const uint2*>(&pb);
    }
  }
  // l partial (per row, identical across 16 lanes)
  if (lr==0){
    #pragma unroll
    for (int r=0;r<4;r++)
      lpart[((size_t)z*16 + bkv)*SEQ + rowt + lk*4 + r] = accl[r];
  }
  // unnormalized PV partial, lane-contiguous (1KB/instr)
  float* base = pvpart + (((size_t)z*16 + bkv)*128 + blockIdx.x*2 + w)*1024;
  #pragma unroll
  for (int dt=0; dt<4; dt++)
    *reinterpret_cast<f32x4*>(base + (dt*64 + l)*4) = acco[dt];
}

// ---------------- invl = 1/sum_z lpart ---------------------------------------
__global__ __launch_bounds__(256) void k_linv(
    const float* __restrict__ lpart, float* __restrict__ invl)
{
  int idx = blockIdx.x*256 + threadIdx.x;   // < 16*2048
  float s = 0.f;
  #pragma unroll
  for (int z=0; z<NZ; z++) s += lpart[(size_t)z*16*SEQ + idx];
  invl[idx] = 1.0f/s;
}

// ---------------- expand: in-place packed bf16 -> f32 * invl (pure stream) ---
// One wave per attn row. Descending windows make in-place expansion race-free:
// window win reads u32 slots [win*64, win*64+64), writes f32 [win*128,+128);
// remaining reads (< win*64) are always below the write range, and the
// current window's loads complete into registers before its stores issue.
__global__ __launch_bounds__(256) void k_expand(
    float* __restrict__ attn, const float* __restrict__ invl)
{
  int w = threadIdx.x>>6, l = threadIdx.x&63;
  int row = blockIdx.x*4 + w;              // 0..32767 = bkv*2048 + q
  float iv = invl[row];
  unsigned* src = (unsigned*)(attn + (size_t)row*SEQ);
  float* dst = attn + (size_t)row*SEQ;
  for (int win=15; win>=0; --win){
    unsigned pv = src[win*64 + l];
    float2 o;
    o.x = bf2f((unsigned short)(pv & 0xFFFFu))*iv;
    o.y = bf2f((unsigned short)(pv >> 16))*iv;
    *reinterpret_cast<float2*>(&dst[(size_t)(win*64 + l)*2]) = o;
  }
}

// ---------------- sum PV partials * invl -> X --------------------------------
__global__ __launch_bounds__(256) void k_pvred(
    const float* __restrict__ pvpart, const float* __restrict__ invl,
    float* __restrict__ X)
{
  __shared__ float xls[16][65];
  int T = blockIdx.x;                  // bkv*128 + wt
  int wt = T & 127, bkv = T>>7;
  int b = bkv>>2, kv = bkv&3;
  int t = threadIdx.x, l = t&63, dt = t>>6, lk = l>>4, lr = l&15;
  f32x4 s = {0.f,0.f,0.f,0.f};
  #pragma unroll
  for (int z=0; z<NZ; z++){
    f32x4 v = *reinterpret_cast<const f32x4*>(
        pvpart + (((size_t)z*16 + bkv)*128 + wt)*1024 + t*4);
    s += v;
  }
  float iv[4];
  #pragma unroll
  for (int r=0; r<4; r++) iv[r] = invl[(size_t)bkv*SEQ + wt*16 + lk*4 + r];
  #pragma unroll
  for (int r=0; r<4; r++) xls[lk*4+r][dt*16+lr] = s[r]*iv[r];
  __syncthreads();
  int row = t>>4, col4 = (t&15)*4;
  float4 o;
  o.x = xls[row][col4];   o.y = xls[row][col4+1];
  o.z = xls[row][col4+2]; o.w = xls[row][col4+3];
  *reinterpret_cast<float4*>(
      &X[((size_t)(b*SEQ + wt*16 + row))*KV_MODELC + kv*64 + col4]) = o;
}

// -----------------------------------------------------------------------------
extern "C" void kernel_launch(void* const* d_in, const int* in_sizes, int n_in,
                              void* d_out, int out_size, void* d_ws, size_t ws_size,
                              hipStream_t stream)
{
  (void)in_sizes; (void)n_in; (void)out_size; (void)ws_size;
  const float* q  = (const float*)d_in[0];
  const float* k  = (const float*)d_in[1];
  const float* v  = (const float*)d_in[2];
  const float* Wq = (const float*)d_in[3];
  const float* bq = (const float*)d_in[4];
  const float* Wk = (const float*)d_in[5];
  const float* bk = (const float*)d_in[6];
  const float* Wv = (const float*)d_in[7];
  const float* bv = (const float*)d_in[8];
  const float* Wo = (const float*)d_in[9];
  const float* bo = (const float*)d_in[10];

  float* out_x = (float*)d_out;
  float* out_attn = out_x + (size_t)NTOK*N_MODELC;

  char* ws = (char*)d_ws;
  size_t off = 0;
  auto alloc = [&](size_t bytes)->void*{
    void* p = ws + off; off += (bytes + 255) & ~(size_t)255; return p;
  };
  int8_t* q8q = (int8_t*)alloc((size_t)NTOK*N_MODELC);
  int8_t* q8k = (int8_t*)alloc((size_t)NTOK*N_MODELC);
  int8_t* q8v = (int8_t*)alloc((size_t)NTOK*N_MODELC);
  int8_t* q8x = (int8_t*)alloc((size_t)NTOK*KV_MODELC);
  float* scq = (float*)alloc(NTOK*4);
  float* sck = (float*)alloc(NTOK*4);
  float* scv = (float*)alloc(NTOK*4);
  float* scx = (float*)alloc(NTOK*4);
  float* partial = (float*)alloc(4*256*4);
  float* wfac = (float*)alloc(256);
  int8_t* Wqs = (int8_t*)alloc(256*1024);
  int8_t* Wkt = (int8_t*)alloc(256*1024);
  int8_t* Wvt = (int8_t*)alloc(256*1024);
  int8_t* Wot = (int8_t*)alloc(1024*256);
  unsigned short* Qh = (unsigned short*)alloc((size_t)NTOK*KV_MODELC*2);
  unsigned short* Kh = (unsigned short*)alloc((size_t)NTOK*KV_MODELC*2);
  unsigned short* Vh = (unsigned short*)alloc((size_t)NTOK*KV_MODELC*2);
  float* X = (float*)alloc((size_t)NTOK*KV_MODELC*4);
  float* lpart = (float*)alloc((size_t)NZ*16*SEQ*4);              // 512 KB
  float* invl  = (float*)alloc((size_t)16*SEQ*4);                 // 128 KB
  float* pvpart = (float*)alloc((size_t)NZ*16*128*1024*4);        // 33.5 MB

  // 1. act quant of q,k,v
  hipLaunchKernelGGL(k_actquant1024, dim3(NTOK,3), dim3(256), 0, stream,
                     q,k,v, q8q,q8k,q8v, scq,sck,scv);
  // 2-3. weight absmean
  hipLaunchKernelGGL(k_wabs_partial, dim3(256,4), dim3(256), 0, stream, Wq,Wk,Wv,Wo, partial);
  hipLaunchKernelGGL(k_wfinal, dim3(4), dim3(256), 0, stream, partial, wfac);
  // 4. ternarize
  hipLaunchKernelGGL(k_tern, dim3(1024,4), dim3(256), 0, stream,
                     Wq,Wk,Wv,Wo, wfac, Wqs,Wkt,Wvt,Wot);
  // 5-7. projections (int8 MFMA, head-packed epilogues)
  hipLaunchKernelGGL((k_gemm_i8_1024<0>), dim3(128,4), dim3(512), 0, stream,
                     q8q, Wqs, scq, wfac, 0, bq, Qh);
  hipLaunchKernelGGL((k_gemm_i8_1024<1>), dim3(128,4), dim3(512), 0, stream,
                     q8k, Wkt, sck, wfac, 1, bk, Kh);
  hipLaunchKernelGGL((k_gemm_i8_1024<2>), dim3(128,4), dim3(512), 0, stream,
                     q8v, Wvt, scv, wfac, 2, bv, Vh);
  // 8a. single-pass attention: packed p~ + l partials + PV partials
  hipLaunchKernelGGL(k_attn_pv2, dim3(64,16,NZ), dim3(128), 0, stream,
                     Qh, Kh, Vh, out_attn, lpart, pvpart);
  // 8b. invl
  hipLaunchKernelGGL(k_linv, dim3(16*SEQ/256), dim3(256), 0, stream, lpart, invl);
  // 8c. in-place expand packed bf16 -> f32 * invl (pure stream)
  hipLaunchKernelGGL(k_expand, dim3(16*SEQ/4), dim3(256), 0, stream,
                     out_attn, invl);
  // 8d. reduce PV partials * invl -> X
  hipLaunchKernelGGL(k_pvred, dim3(2048), dim3(256), 0, stream, pvpart, invl, X);
  // 9. act quant of x
  hipLaunchKernelGGL(k_actquant256, dim3(NTOK), dim3(64), 0, stream, X, q8x, scx);
  // 10. output bitlinear -> d_out x
  hipLaunchKernelGGL(k_gemm_o, dim3(128,16), dim3(256), 0, stream,
                     q8x, Wot, scx, wfac, bo, out_x);
}

// Round 14
// 300.479 us; speedup vs baseline: 1.1536x; 1.1536x over previous
//
#include <hip/hip_runtime.h>
#include <stdint.h>

#define N_MODELC 1024
#define KV_MODELC 256
#define BATCH 4
#define SEQ 2048
#define NTOK (BATCH*SEQ)   // 8192

typedef __attribute__((ext_vector_type(4))) float f32x4;
typedef __attribute__((ext_vector_type(4))) int   i32x4;
typedef __attribute__((ext_vector_type(8))) short s16x8;
typedef __attribute__((ext_vector_type(4))) short s16x4;

#define LOG2E 1.4426950408889634f
#define PSHIFT 32.0f

__device__ __forceinline__ unsigned short f2bf(float f){
  unsigned u = __builtin_bit_cast(unsigned, f);
  u = (u + 0x7FFFu + ((u>>16)&1u)) >> 16;
  return (unsigned short)u;
}
__device__ __forceinline__ float bf2f(unsigned short b){
  return __builtin_bit_cast(float, ((unsigned)b)<<16);
}

// ---------------- activation rmsnorm + int8 absmax quant (1024-wide rows) ----
__global__ __launch_bounds__(256) void k_actquant1024(
    const float* __restrict__ xq_in, const float* __restrict__ xk_in, const float* __restrict__ xv_in,
    int8_t* __restrict__ q8q, int8_t* __restrict__ q8k, int8_t* __restrict__ q8v,
    float* __restrict__ scq, float* __restrict__ sck, float* __restrict__ scv)
{
  int row = blockIdx.x, which = blockIdx.y, t = threadIdx.x;
  const float* x = (which==0)?xq_in:(which==1)?xk_in:xv_in;
  int8_t* q8 = (which==0)?q8q:(which==1)?q8k:q8v;
  float* sc = (which==0)?scq:(which==1)?sck:scv;
  const float* xr = x + (size_t)row*N_MODELC;
  float4 v = reinterpret_cast<const float4*>(xr)[t];
  float ss = v.x*v.x + v.y*v.y + v.z*v.z + v.w*v.w;
  float am = fmaxf(fmaxf(fabsf(v.x),fabsf(v.y)), fmaxf(fabsf(v.z),fabsf(v.w)));
  #pragma unroll
  for (int m=32;m;m>>=1){ ss += __shfl_xor(ss,m,64); am = fmaxf(am, __shfl_xor(am,m,64)); }
  __shared__ float red[8];
  int wid = t>>6;
  if ((t&63)==0){ red[wid]=ss; red[4+wid]=am; }
  __syncthreads();
  ss = red[0]+red[1]+red[2]+red[3];
  am = fmaxf(fmaxf(red[4],red[5]), fmaxf(red[6],red[7]));
  float rinv = rsqrtf(ss*(1.0f/N_MODELC) + 1e-6f);
  float clipv = fmaxf(am*rinv, 1e-5f);
  float qs = 127.0f/clipv;
  float fsc = rinv*qs;
  char4 o;
  o.x = (signed char)(int)fminf(127.f, fmaxf(-128.f, rintf(v.x*fsc)));
  o.y = (signed char)(int)fminf(127.f, fmaxf(-128.f, rintf(v.y*fsc)));
  o.z = (signed char)(int)fminf(127.f, fmaxf(-128.f, rintf(v.z*fsc)));
  o.w = (signed char)(int)fminf(127.f, fmaxf(-128.f, rintf(v.w*fsc)));
  reinterpret_cast<char4*>(q8 + (size_t)row*N_MODELC)[t] = o;
  if (t==0) sc[row] = clipv*(1.0f/127.0f);
}

// ---------------- same for 256-wide rows (one wave per row) ------------------
__global__ __launch_bounds__(64) void k_actquant256(
    const float* __restrict__ X, int8_t* __restrict__ q8, float* __restrict__ sc)
{
  int row = blockIdx.x, l = threadIdx.x;
  float4 v = reinterpret_cast<const float4*>(X + (size_t)row*KV_MODELC)[l];
  float ss = v.x*v.x + v.y*v.y + v.z*v.z + v.w*v.w;
  float am = fmaxf(fmaxf(fabsf(v.x),fabsf(v.y)), fmaxf(fabsf(v.z),fabsf(v.w)));
  #pragma unroll
  for (int m=32;m;m>>=1){ ss += __shfl_xor(ss,m,64); am = fmaxf(am, __shfl_xor(am,m,64)); }
  float rinv = rsqrtf(ss*(1.0f/KV_MODELC) + 1e-6f);
  float clipv = fmaxf(am*rinv, 1e-5f);
  float qs = 127.0f/clipv;
  float fsc = rinv*qs;
  char4 o;
  o.x = (signed char)(int)fminf(127.f, fmaxf(-128.f, rintf(v.x*fsc)));
  o.y = (signed char)(int)fminf(127.f, fmaxf(-128.f, rintf(v.y*fsc)));
  o.z = (signed char)(int)fminf(127.f, fmaxf(-128.f, rintf(v.z*fsc)));
  o.w = (signed char)(int)fminf(127.f, fmaxf(-128.f, rintf(v.w*fsc)));
  reinterpret_cast<char4*>(q8 + (size_t)row*KV_MODELC)[l] = o;
  if (l==0) sc[row] = clipv*(1.0f/127.0f);
}

// ---------------- weight absmean: stage 1 ------------------------------------
__global__ __launch_bounds__(256) void k_wabs_partial(
    const float* __restrict__ Wq, const float* __restrict__ Wk,
    const float* __restrict__ Wv, const float* __restrict__ Wo, float* __restrict__ partial)
{
  int mat = blockIdx.y;
  const float* w = (mat==0)?Wq:(mat==1)?Wk:(mat==2)?Wv:Wo;
  int n = (mat==0)?(N_MODELC*N_MODELC):(KV_MODELC*N_MODELC);
  float s = 0.f;
  for (int i = blockIdx.x*256 + threadIdx.x; i < n; i += 256*256) s += fabsf(w[i]);
  #pragma unroll
  for (int m=32;m;m>>=1) s += __shfl_xor(s,m,64);
  __shared__ float red[4];
  int wid = threadIdx.x>>6;
  if ((threadIdx.x&63)==0) red[wid]=s;
  __syncthreads();
  if (threadIdx.x==0) partial[mat*256 + blockIdx.x] = red[0]+red[1]+red[2]+red[3];
}

// ---------------- weight absmean: stage 2 ------------------------------------
__global__ __launch_bounds__(256) void k_wfinal(const float* __restrict__ partial, float* __restrict__ wfac)
{
  int mat = blockIdx.x, t = threadIdx.x;
  float s = partial[mat*256 + t];
  #pragma unroll
  for (int m=32;m;m>>=1) s += __shfl_xor(s,m,64);
  __shared__ float red[4];
  int wid = t>>6;
  if ((t&63)==0) red[wid]=s;
  __syncthreads();
  if (t==0){
    float tot = red[0]+red[1]+red[2]+red[3];
    float n = (mat==0)?(float)(N_MODELC*N_MODELC):(float)(KV_MODELC*N_MODELC);
    wfac[mat] = fmaxf(tot/n, 1e-5f);
  }
}

// ---------------- ternarize weights (Wq also group-summed) -------------------
__global__ __launch_bounds__(256) void k_tern(
    const float* __restrict__ Wq, const float* __restrict__ Wk,
    const float* __restrict__ Wv, const float* __restrict__ Wo,
    const float* __restrict__ wfac,
    int8_t* __restrict__ Wqs, int8_t* __restrict__ Wkt,
    int8_t* __restrict__ Wvt, int8_t* __restrict__ Wot)
{
  int mat = blockIdx.y;
  int idx = blockIdx.x*256 + threadIdx.x;
  if (mat==0){
    float s = 1.0f/wfac[0];
    int op = idx>>10, i = idx&1023;
    int kv = op>>6, d = op&63;
    int acc = 0;
    #pragma unroll
    for (int g=0; g<4; g++){
      float w = Wq[(size_t)(kv*256 + g*64 + d)*N_MODELC + i];
      float r = fminf(1.f, fmaxf(-1.f, rintf(w*s)));
      acc += (int)r;
    }
    Wqs[idx] = (int8_t)acc;
  } else {
    const float* w = (mat==1)?Wk:(mat==2)?Wv:Wo;
    int8_t* o = (mat==1)?Wkt:(mat==2)?Wvt:Wot;
    float s = 1.0f/wfac[mat];
    float r = fminf(1.f, fmaxf(-1.f, rintf(w[idx]*s)));
    o[idx] = (int8_t)r;
  }
}

// ---------------- int8 GEMM (K=1024), 8 waves, k-split -----------------------
// MODE 0: Q -> bf16 head-packed Qh[bkv][s][64], x0.125, group-summed bias
// MODE 1: K -> bf16 head-packed Kh[bkv][s][64]
// MODE 2: V -> bf16 head-tiled Vh[bkv][sTile][64d][64s] via LDS transpose
template<int MODE>
__global__ __launch_bounds__(512) void k_gemm_i8_1024(
    const int8_t* __restrict__ A, const int8_t* __restrict__ B,
    const float* __restrict__ rowscale, const float* __restrict__ wfac, int wfi,
    const float* __restrict__ bias, unsigned short* __restrict__ outp)
{
  __shared__ i32x4 redk[4][4][64];                      // 16 KB
  __shared__ unsigned short tlds[(MODE==2)?64:1][72];
  const int KDIM = 1024;
  int mb = blockIdx.x*64, nb = blockIdx.y*64;
  int w = threadIdx.x>>6, l = threadIdx.x&63, lr = l&15, lk = l>>4;
  int rw = w&3, kh = w>>2;
  const int8_t* Ap = A + (size_t)(mb + rw*16 + lr)*KDIM + kh*512 + lk*16;
  const int8_t* Bp = B + (size_t)(nb + lr)*KDIM + kh*512 + lk*16;
  i32x4 acc[4];
  #pragma unroll
  for (int f=0; f<4; f++) acc[f] = i32x4{0,0,0,0};
  #pragma unroll 4
  for (int kk=0; kk<512; kk+=64){
    i32x4 a = *reinterpret_cast<const i32x4*>(Ap + kk);
    #pragma unroll
    for (int f=0; f<4; f++){
      i32x4 b = *reinterpret_cast<const i32x4*>(Bp + (size_t)f*16*KDIM + kk);
      acc[f] = __builtin_amdgcn_mfma_i32_16x16x64_i8(a, b, acc[f], 0, 0, 0);
    }
  }
  if (kh==1){
    #pragma unroll
    for (int f=0; f<4; f++) redk[rw][f][l] = acc[f];
  }
  __syncthreads();
  if (kh==0){
    float wf = wfac[wfi];
    #pragma unroll
    for (int f=0; f<4; f++){
      acc[f] += redk[rw][f][l];
      int col = nb + f*16 + lr;
      float bval;
      if constexpr (MODE==0){
        int kv = col>>6, d = col&63;
        const float* bb = bias + kv*256 + d;
        bval = bb[0]+bb[64]+bb[128]+bb[192];
      } else {
        bval = bias[col];
      }
      #pragma unroll
      for (int r=0; r<4; r++){
        int row = mb + rw*16 + lk*4 + r;
        float val = (float)acc[f][r] * (rowscale[row]*wf) + bval;
        if constexpr (MODE==0){
          int bb2 = row>>11, s = row&2047, kvh = col>>6, d = col&63;
          outp[(((size_t)(bb2*4+kvh))*SEQ + s)*64 + d] = f2bf(0.125f*val);
        } else if constexpr (MODE==1){
          int bb2 = row>>11, s = row&2047, kvh = col>>6, d = col&63;
          outp[(((size_t)(bb2*4+kvh))*SEQ + s)*64 + d] = f2bf(val);
        } else {
          tlds[f*16+lr][rw*16 + lk*4 + r] = f2bf(val);
        }
      }
    }
  }
  if constexpr (MODE==2){
    __syncthreads();
    int u = threadIdx.x;
    int col = u>>3, part = u&7;
    int b = mb>>11, s0 = mb&2047;
    int bkv = b*4 + blockIdx.y, sT = s0>>6;
    s16x8 vv = *reinterpret_cast<const s16x8*>(&tlds[col][part*8]);
    *reinterpret_cast<s16x8*>(
        &outp[(((size_t)(bkv*32 + sT))*64 + col)*64 + part*8]) = vv;
  }
}

// ---------------- int8 GEMM (K=256) output bitlinear -> f32 d_out ------------
__global__ __launch_bounds__(256) void k_gemm_o(
    const int8_t* __restrict__ A, const int8_t* __restrict__ B,
    const float* __restrict__ rowscale, const float* __restrict__ wfac,
    const float* __restrict__ bias, float* __restrict__ outp)
{
  const int KDIM = 256;
  int mb = blockIdx.x*64, nb = blockIdx.y*64;
  int w = threadIdx.x>>6, l = threadIdx.x&63, lr = l&15, lk = l>>4;
  const int8_t* Ap = A + (size_t)(mb + w*16 + lr)*KDIM + lk*16;
  const int8_t* Bp = B + (size_t)(nb + lr)*KDIM + lk*16;
  i32x4 acc[4];
  #pragma unroll
  for (int f=0; f<4; f++) acc[f] = i32x4{0,0,0,0};
  #pragma unroll
  for (int kk=0; kk<KDIM; kk+=64){
    i32x4 a = *reinterpret_cast<const i32x4*>(Ap + kk);
    #pragma unroll
    for (int f=0; f<4; f++){
      i32x4 b = *reinterpret_cast<const i32x4*>(Bp + (size_t)f*16*KDIM + kk);
      acc[f] = __builtin_amdgcn_mfma_i32_16x16x64_i8(a, b, acc[f], 0, 0, 0);
    }
  }
  float wf = wfac[3];
  #pragma unroll
  for (int f=0; f<4; f++){
    int col = nb + f*16 + lr;
    float bval = bias[col];
    #pragma unroll
    for (int r=0; r<4; r++){
      int row = mb + w*16 + lk*4 + r;
      outp[(size_t)row*N_MODELC + col] = (float)acc[f][r]*(rowscale[row]*wf) + bval;
    }
  }
}

// ---------------- attention: R10 structure + XCD-grouped bkv + nt stores -----
// Fixed-shift softmax: p = 2^(e*log2e-32)/l, l complete after pass 1 via
// ones-MFMA. Block = 128 thr (2 waves), 16 q-rows/wave, full s.
// Grid = 1024 flat; bkv = ((i&7)<<1)|((i>>3)&1) so all 64 q-blocks of one
// bkv land on one XCD (dispatch round-robins XCDs by block index) -> each
// XCD's L2 holds only 2 heads' K+V (1 MB) instead of 16 (8 MB).
// Pass 2 probs stores are nontemporal (never re-read; keep K/V in L2).
__global__ __launch_bounds__(128) void k_attn_full(
    const unsigned short* __restrict__ Qh, const unsigned short* __restrict__ Kh,
    const unsigned short* __restrict__ Vh,
    float* __restrict__ attn, float* __restrict__ X)
{
  __shared__ unsigned short plds[2][16][64];   // 4 KB, wave-private tiles
  int i = blockIdx.x;                          // 0..1023
  int bkv = ((i&7)<<1) | ((i>>3)&1);           // XCD-grouped head index
  int qb  = i>>4;                              // 0..63
  int b = bkv>>2, kv = bkv&3;
  int w = threadIdx.x>>6, l = threadIdx.x&63, lr = l&15, lk = l>>4;
  int rowt = qb*32 + w*16;
  size_t tq = ((size_t)bkv*SEQ + rowt + lr)*64 + lk*8;
  s16x8 qa0 = *reinterpret_cast<const s16x8*>(Qh + tq);
  s16x8 qa1 = *reinterpret_cast<const s16x8*>(Qh + tq + 32);
  const unsigned short* kbase = Kh + (size_t)bkv*SEQ*64 + lk*8;
  const unsigned short* vbase = Vh + (size_t)bkv*32*4096 + lk*8;

  s16x8 ones;
  #pragma unroll
  for (int j=0;j<8;j++) ones[j] = (short)0x3F80;   // bf16 1.0

  f32x4 acco[4];
  #pragma unroll
  for (int dt=0; dt<4; dt++) acco[dt] = f32x4{0.f,0.f,0.f,0.f};
  f32x4 accl = {0.f,0.f,0.f,0.f};

  int qwl = lk*4;                 // local write-row base (+r)
  int rswl = (lr&7)<<3;           // PV read swizzle base (local row = lr)

  // ---- pass 1: P-tilde -> PV + l (no global stores) ----
  for (int st=0; st<SEQ; st+=64){
    #pragma unroll
    for (int sub=0; sub<4; sub++){
      int s0 = st + sub*16;
      const unsigned short* kp = kbase + (size_t)(s0+lr)*64;
      s16x8 k0 = *reinterpret_cast<const s16x8*>(kp);
      s16x8 k1 = *reinterpret_cast<const s16x8*>(kp + 32);
      f32x4 acc = {0.f,0.f,0.f,0.f};
      acc = __builtin_amdgcn_mfma_f32_16x16x32_bf16(qa0, k0, acc, 0,0,0);
      acc = __builtin_amdgcn_mfma_f32_16x16x32_bf16(qa1, k1, acc, 0,0,0);
      int slocal = sub*16 + lr;
      #pragma unroll
      for (int r=0;r<4;r++){
        float p = __builtin_amdgcn_exp2f(fmaf(acc[r], LOG2E, -PSHIFT));
        int sw = (slocal & 7) | ((((slocal>>3) ^ ((qwl+r)&7)))<<3);
        plds[w][qwl + r][sw] = f2bf(p);
      }
    }
    s16x8 a0 = *reinterpret_cast<const s16x8*>(&plds[w][lr][(lk<<3) ^ rswl]);
    s16x8 a1 = *reinterpret_cast<const s16x8*>(&plds[w][lr][((4+lk)<<3) ^ rswl]);
    accl = __builtin_amdgcn_mfma_f32_16x16x32_bf16(a0, ones, accl, 0,0,0);
    accl = __builtin_amdgcn_mfma_f32_16x16x32_bf16(a1, ones, accl, 0,0,0);
    const unsigned short* vt = vbase + (size_t)(st>>6)*4096;
    #pragma unroll
    for (int dt=0; dt<4; dt++){
      const unsigned short* vp = vt + (size_t)(dt*16+lr)*64;
      s16x8 b0 = *reinterpret_cast<const s16x8*>(vp);
      s16x8 b1 = *reinterpret_cast<const s16x8*>(vp + 32);
      acco[dt] = __builtin_amdgcn_mfma_f32_16x16x32_bf16(a0, b0, acco[dt], 0,0,0);
      acco[dt] = __builtin_amdgcn_mfma_f32_16x16x32_bf16(a1, b1, acco[dt], 0,0,0);
    }
  }

  // invl (fully in-register: lane holds rows qwl..qwl+3) and X write
  float invr[4];
  #pragma unroll
  for (int r=0;r<4;r++) invr[r] = 1.0f/accl[r];
  int token = b*SEQ + rowt + qwl;
  #pragma unroll
  for (int dt=0; dt<4; dt++){
    #pragma unroll
    for (int r=0; r<4; r++){
      X[(size_t)(token + r)*KV_MODELC + kv*64 + dt*16 + lr] = acco[dt][r]*invr[r];
    }
  }

  // ---- pass 2: recompute energy, normalized probs -> nt coalesced stores ----
  float* arow = attn + (size_t)bkv*SEQ*SEQ + (size_t)rowt*SEQ;
  for (int st=0; st<SEQ; st+=64){
    #pragma unroll
    for (int sub=0; sub<4; sub++){
      int s0 = st + sub*16;
      const unsigned short* kp = kbase + (size_t)(s0+lr)*64;
      s16x8 k0 = *reinterpret_cast<const s16x8*>(kp);
      s16x8 k1 = *reinterpret_cast<const s16x8*>(kp + 32);
      f32x4 acc = {0.f,0.f,0.f,0.f};
      acc = __builtin_amdgcn_mfma_f32_16x16x32_bf16(qa0, k0, acc, 0,0,0);
      acc = __builtin_amdgcn_mfma_f32_16x16x32_bf16(qa1, k1, acc, 0,0,0);
      int slocal = sub*16 + lr;
      #pragma unroll
      for (int r=0;r<4;r++){
        float p = __builtin_amdgcn_exp2f(fmaf(acc[r], LOG2E, -PSHIFT))*invr[r];
        int sw = (slocal & 7) | ((((slocal>>3) ^ ((qwl+r)&7)))<<3);
        plds[w][qwl + r][sw] = f2bf(p);
      }
    }
    // readback: 16 lanes x f32x4 = 256B contiguous per row (R6-proven),
    // nontemporal (probs never re-read; keep K/V resident in L2/L3)
    #pragma unroll
    for (int j=0; j<4; j++){
      int rowl = j*4 + (l>>4);
      int sseg = l & 15;
      int chunk = sseg >> 1, half = sseg & 1;
      int off = ((chunk ^ (rowl&7)) << 3) + (half<<2);
      s16x4 pb = *reinterpret_cast<const s16x4*>(&plds[w][rowl][off]);
      f32x4 o;
      o[0] = bf2f((unsigned short)pb[0]);
      o[1] = bf2f((unsigned short)pb[1]);
      o[2] = bf2f((unsigned short)pb[2]);
      o[3] = bf2f((unsigned short)pb[3]);
      __builtin_nontemporal_store(o,
          reinterpret_cast<f32x4*>(&arow[(size_t)rowl*SEQ + st + sseg*4]));
    }
  }
}

// -----------------------------------------------------------------------------
extern "C" void kernel_launch(void* const* d_in, const int* in_sizes, int n_in,
                              void* d_out, int out_size, void* d_ws, size_t ws_size,
                              hipStream_t stream)
{
  (void)in_sizes; (void)n_in; (void)out_size; (void)ws_size;
  const float* q  = (const float*)d_in[0];
  const float* k  = (const float*)d_in[1];
  const float* v  = (const float*)d_in[2];
  const float* Wq = (const float*)d_in[3];
  const float* bq = (const float*)d_in[4];
  const float* Wk = (const float*)d_in[5];
  const float* bk = (const float*)d_in[6];
  const float* Wv = (const float*)d_in[7];
  const float* bv = (const float*)d_in[8];
  const float* Wo = (const float*)d_in[9];
  const float* bo = (const float*)d_in[10];

  float* out_x = (float*)d_out;
  float* out_attn = out_x + (size_t)NTOK*N_MODELC;

  char* ws = (char*)d_ws;
  size_t off = 0;
  auto alloc = [&](size_t bytes)->void*{
    void* p = ws + off; off += (bytes + 255) & ~(size_t)255; return p;
  };
  int8_t* q8q = (int8_t*)alloc((size_t)NTOK*N_MODELC);
  int8_t* q8k = (int8_t*)alloc((size_t)NTOK*N_MODELC);
  int8_t* q8v = (int8_t*)alloc((size_t)NTOK*N_MODELC);
  int8_t* q8x = (int8_t*)alloc((size_t)NTOK*KV_MODELC);
  float* scq = (float*)alloc(NTOK*4);
  float* sck = (float*)alloc(NTOK*4);
  float* scv = (float*)alloc(NTOK*4);
  float* scx = (float*)alloc(NTOK*4);
  float* partial = (float*)alloc(4*256*4);
  float* wfac = (float*)alloc(256);
  int8_t* Wqs = (int8_t*)alloc(256*1024);
  int8_t* Wkt = (int8_t*)alloc(256*1024);
  int8_t* Wvt = (int8_t*)alloc(256*1024);
  int8_t* Wot = (int8_t*)alloc(1024*256);
  unsigned short* Qh = (unsigned short*)alloc((size_t)NTOK*KV_MODELC*2);
  unsigned short* Kh = (unsigned short*)alloc((size_t)NTOK*KV_MODELC*2);
  unsigned short* Vh = (unsigned short*)alloc((size_t)NTOK*KV_MODELC*2);
  float* X = (float*)alloc((size_t)NTOK*KV_MODELC*4);

  // 1. act quant of q,k,v
  hipLaunchKernelGGL(k_actquant1024, dim3(NTOK,3), dim3(256), 0, stream,
                     q,k,v, q8q,q8k,q8v, scq,sck,scv);
  // 2-3. weight absmean
  hipLaunchKernelGGL(k_wabs_partial, dim3(256,4), dim3(256), 0, stream, Wq,Wk,Wv,Wo, partial);
  hipLaunchKernelGGL(k_wfinal, dim3(4), dim3(256), 0, stream, partial, wfac);
  // 4. ternarize
  hipLaunchKernelGGL(k_tern, dim3(1024,4), dim3(256), 0, stream,
                     Wq,Wk,Wv,Wo, wfac, Wqs,Wkt,Wvt,Wot);
  // 5-7. projections (int8 MFMA, head-packed epilogues)
  hipLaunchKernelGGL((k_gemm_i8_1024<0>), dim3(128,4), dim3(512), 0, stream,
                     q8q, Wqs, scq, wfac, 0, bq, Qh);
  hipLaunchKernelGGL((k_gemm_i8_1024<1>), dim3(128,4), dim3(512), 0, stream,
                     q8k, Wkt, sck, wfac, 1, bk, Kh);
  hipLaunchKernelGGL((k_gemm_i8_1024<2>), dim3(128,4), dim3(512), 0, stream,
                     q8v, Wvt, scv, wfac, 2, bv, Vh);
  // 8. attention: XCD-grouped heads, nt probs stores
  hipLaunchKernelGGL(k_attn_full, dim3(1024), dim3(128), 0, stream,
                     Qh, Kh, Vh, out_attn, X);
  // 9. act quant of x
  hipLaunchKernelGGL(k_actquant256, dim3(NTOK), dim3(64), 0, stream, X, q8x, scx);
  // 10. output bitlinear -> d_out x
  hipLaunchKernelGGL(k_gemm_o, dim3(128,16), dim3(256), 0, stream,
                     q8x, Wot, scx, wfac, bo, out_x);
}